// Round 5
// baseline (56.497 us; speedup 1.0000x reference)
//
#include <hip/hip_runtime.h>

typedef _Float16 half8  __attribute__((ext_vector_type(8)));
typedef float    float4_t __attribute__((ext_vector_type(4)));

#define SH 4
#define SW 160
#define CW (SW + 2)   // 162 staged cv cols
#define NR (SH + 2)   // 6 staged rows
#define DW (CW + 1)   // 163: depth LDS row stride (odd for bank spread)

__device__ __forceinline__ float fexp2(float x) {
    float r;
    asm volatile("v_exp_f32 %0, %1" : "=v"(r) : "v"(x));
    return r;
}

__global__ __launch_bounds__(256, 6) void depth_up_fused(
    const float* __restrict__ depth,
    const float* __restrict__ cv,
    const float* __restrict__ w1,   // [8,8,3,3]
    const float* __restrict__ b1,   // [8]
    const float* __restrict__ w2,   // [36,8]
    const float* __restrict__ b2,   // [36]
    float* __restrict__ out)        // [N, 1024, 1280]
{
    const int H = 512, W = 640;
    const size_t HW = (size_t)H * W;
    const int n  = blockIdx.z;
    const int h0 = blockIdx.y * SH;
    const int cb = blockIdx.x * SW;
    const int tid  = threadIdx.x;
    const int lane = tid & 63;
    const int wv   = tid >> 6;       // wave = row within strip
    const int o    = lane & 15;
    const int krow = lane >> 4;
    const int u    = o >> 2;         // tap-group
    const int q    = o & 3;          // softmax column

    __shared__ half8 s_cv[NR * CW];  // 15,552 B
    __shared__ float s_d[NR * DW];   //  3,912 B

    const float* __restrict__ cvn = cv + (size_t)n * 8 * HW;
    const float* __restrict__ dn  = depth + (size_t)n * HW;

    // ---- stage cv (fp16x8, [row][col][ch]) + depth (f32) with zero halo ----
    for (int i = tid; i < NR * CW; i += 256) {
        const int r = i / CW;
        const int c = i - r * CW;
        const int gh = h0 + r - 1;
        const int gw = cb + c - 1;
        half8 hv = {};
        float dv = 0.0f;
        if ((unsigned)gh < (unsigned)H && (unsigned)gw < (unsigned)W) {
            const float* p = cvn + (size_t)gh * W + gw;
            #pragma unroll
            for (int ch = 0; ch < 8; ++ch) hv[ch] = (_Float16)p[(size_t)ch * HW];
            dv = dn[(size_t)gh * W + gw];
        }
        s_cv[i] = hv;
        s_d[r * DW + c] = dv;
    }

    // ---- conv1 weights as A-fragments: A1[row=och][k], k = tap*8 + c ----
    half8 a1[3];
    #pragma unroll
    for (int ki = 0; ki < 3; ++ki) {
        const int tap = 4 * ki + krow;
        #pragma unroll
        for (int j = 0; j < 8; ++j)
            a1[ki][j] = (tap < 9 && o < 8) ? (_Float16)w1[(o * 8 + j) * 9 + tap]
                                           : (_Float16)0.0f;
    }
    // cv B-fragment per-lane base byte offsets
    int aoff[3];
    #pragma unroll
    for (int ki = 0; ki < 3; ++ki) {
        const int tap0 = 4 * ki + krow;
        const int tap  = tap0 > 8 ? 8 : tap0;
        const int ky   = tap / 3;
        const int kx   = tap - 3 * ky;
        aoff[ki] = ((wv + ky) * CW + o + kx) * 16;
    }
    // b1 for this lane's 4 och (valid for krow<2; others unused junk)
    const float4_t b1q = *reinterpret_cast<const float4_t*>(b1 + (krow & 1) * 4);

    // ---- conv2 weights as B-fragments (only k=0..7 rows live -> krow==0) ----
    half8 b2f[3] = {};
    if (krow == 0) {
        #pragma unroll
        for (int t = 0; t < 3; ++t) {
            const int m = (o + 16 * t) > 35 ? 35 : (o + 16 * t);
            const float4_t wlo = *reinterpret_cast<const float4_t*>(w2 + m * 8);
            const float4_t whi = *reinterpret_cast<const float4_t*>(w2 + m * 8 + 4);
            #pragma unroll
            for (int j = 0; j < 4; ++j) {
                b2f[t][j]     = (_Float16)wlo[j];
                b2f[t][4 + j] = (_Float16)whi[j];
            }
        }
    }
    // 0.25 * log2(e) folded scale; bias pre-scaled into log2 domain
    const float C = 0.25f * 1.44269504f;
    float b2q[3];
    #pragma unroll
    for (int t = 0; t < 3; ++t) {
        const int m = (o + 16 * t) > 35 ? 35 : (o + 16 * t);
        b2q[t] = C * b2[m];
    }
    const bool t2ok = (u == 0);

    // patch tap byte-offsets in s_d (lane-constant): taps {u, u+4, 8}
    int poff[3];
    {
        const int taps[3] = {u, u + 4, 8};
        #pragma unroll
        for (int t = 0; t < 3; ++t) {
            const int ky = taps[t] / 3;
            const int kx = taps[t] - 3 * ky;
            poff[t] = ((wv + ky) * DW + kx) * 4;
        }
    }

    __syncthreads();

    const char* cvb = (const char*)s_cv;
    const char* sdb = (const char*)s_d;
    const float4_t zero4 = {0.0f, 0.0f, 0.0f, 0.0f};

    // ---- 10 sets of 16 pixels per wave-row; unroll 2 for cross-set ILP ----
    #pragma unroll 2
    for (int ps = 0; ps < SW / 16; ++ps) {
        // conv1: D1[och][pix]  (A = weights, B = cv tile)
        float4_t acc1 = zero4;
        #pragma unroll
        for (int ki = 0; ki < 3; ++ki) {
            const half8 bcv = *(const half8*)(cvb + aoff[ki] + ps * 256);
            acc1 = __builtin_amdgcn_mfma_f32_16x16x32_f16(a1[ki], bcv, acc1, 0, 0, 0);
        }

        // X = relu(acc1 + b1); pack to fp16; xor-16 exchange completes A2 (k=0..7)
        union { half8 v; uint32_t u32[4]; } a2;
        #pragma unroll
        for (int r = 0; r < 4; ++r)
            a2.v[r] = (_Float16)fmaxf(acc1[r] + b1q[r], 0.0f);
        const uint32_t p0 = (uint32_t)__shfl_xor((int)a2.u32[0], 16);
        const uint32_t p1 = (uint32_t)__shfl_xor((int)a2.u32[1], 16);
        a2.u32[2] = p0;
        a2.u32[3] = p1;

        // conv2: D2[pix][m], 3 m-tiles
        float4_t d2[3];
        #pragma unroll
        for (int t = 0; t < 3; ++t)
            d2[t] = __builtin_amdgcn_mfma_f32_16x16x32_f16(a2.v, b2f[t], zero4, 0, 0, 0);

        // mask logits in log2 domain: ml[t][r] = C*d2 + C*b2
        float ml0[4], ml1[4], ml2[4], mx[4];
        #pragma unroll
        for (int r = 0; r < 4; ++r) {
            ml0[r] = fmaf(d2[0][r], C, b2q[0]);
            ml1[r] = fmaf(d2[1][r], C, b2q[1]);
            ml2[r] = t2ok ? fmaf(d2[2][r], C, b2q[2]) : -3.0e38f;
            mx[r]  = fmaxf(fmaxf(ml0[r], ml1[r]), ml2[r]);
        }
        // butterfly max over the 4 tap-group lanes (xor 4, xor 8)
        #pragma unroll
        for (int r = 0; r < 4; ++r) mx[r] = fmaxf(mx[r], __shfl_xor(mx[r], 4));
        #pragma unroll
        for (int r = 0; r < 4; ++r) mx[r] = fmaxf(mx[r], __shfl_xor(mx[r], 8));

        // exps + local weighted sums (patch from depth LDS)
        float se[4], sp[4];
        const int cbase = (ps * 16 + 4 * krow) * 4;
        #pragma unroll
        for (int r = 0; r < 4; ++r) {
            const float e0 = fexp2(ml0[r] - mx[r]);
            const float e1 = fexp2(ml1[r] - mx[r]);
            const float e2 = fexp2(ml2[r] - mx[r]);   // -3e38 path -> 0
            const float pt0 = *(const float*)(sdb + poff[0] + cbase + r * 4);
            const float pt1 = *(const float*)(sdb + poff[1] + cbase + r * 4);
            const float pt2 = *(const float*)(sdb + poff[2] + cbase + r * 4);
            se[r] = e0 + e1 + e2;
            sp[r] = e0 * pt0 + e1 * pt1 + e2 * pt2;
        }
        // butterfly sums
        #pragma unroll
        for (int r = 0; r < 4; ++r) { se[r] += __shfl_xor(se[r], 4); sp[r] += __shfl_xor(sp[r], 4); }
        #pragma unroll
        for (int r = 0; r < 4; ++r) { se[r] += __shfl_xor(se[r], 8); sp[r] += __shfl_xor(sp[r], 8); }

        float res[4];
        #pragma unroll
        for (int r = 0; r < 4; ++r) res[r] = sp[r] * __builtin_amdgcn_rcpf(se[r]);

        // each lane stores its unique (pixel = 4*krow + u, q) output
        const float v01 = (u & 1) ? res[1] : res[0];
        const float v23 = (u & 1) ? res[3] : res[2];
        const float val = (u & 2) ? v23 : v01;
        const int prow = h0 + wv;
        const int pcol = cb + ps * 16 + 4 * krow + u;
        out[((size_t)n * 1024 + (size_t)(2 * prow + (q >> 1))) * 1280
            + (size_t)(2 * pcol + (q & 1))] = val;
    }
}

extern "C" void kernel_launch(void* const* d_in, const int* in_sizes, int n_in,
                              void* d_out, int out_size, void* d_ws, size_t ws_size,
                              hipStream_t stream) {
    (void)in_sizes; (void)n_in; (void)out_size; (void)d_ws; (void)ws_size;
    const float* depth = (const float*)d_in[0];
    const float* cv    = (const float*)d_in[1];
    const float* w1    = (const float*)d_in[2];
    const float* b1    = (const float*)d_in[3];
    const float* w2    = (const float*)d_in[4];
    const float* b2    = (const float*)d_in[5];
    float* out = (float*)d_out;

    dim3 grid(640 / SW, 512 / SH, 4);   // (4, 128, 4) = 2048 blocks
    dim3 block(256);
    hipLaunchKernelGGL(depth_up_fused, grid, block, 0, stream,
                       depth, cv, w1, b1, w2, b2, out);
}

// Round 6
// 45.727 us; speedup vs baseline: 1.2355x; 1.2355x over previous
//
#include <hip/hip_runtime.h>

typedef _Float16 half8  __attribute__((ext_vector_type(8)));
typedef float    float4_t __attribute__((ext_vector_type(4)));

#define SH 4
#define SW 160
#define CW (SW + 2)   // 162 staged cv cols
#define NR (SH + 2)   // 6 staged rows
#define DW (CW + 1)   // 163: depth LDS row stride (odd for bank spread)

__device__ __forceinline__ float fexp2(float x) {
    float r;
    asm volatile("v_exp_f32 %0, %1" : "=v"(r) : "v"(x));
    return r;
}

// VALU-pipe rotate-reduce within each 16-lane row: v += dpp_ror<N>(v)
template <int CTRL>
__device__ __forceinline__ float rr_add(float v) {
    const int i = __float_as_int(v);
    const int p = __builtin_amdgcn_update_dpp(i, i, CTRL, 0xF, 0xF, false);
    return v + __int_as_float(p);
}
#define ROR4 0x124
#define ROR8 0x128

__global__ __launch_bounds__(256, 6) void depth_up_fused(
    const float* __restrict__ depth,
    const float* __restrict__ cv,
    const float* __restrict__ w1,   // [8,8,3,3]
    const float* __restrict__ b1,   // [8]
    const float* __restrict__ w2,   // [36,8]
    const float* __restrict__ b2,   // [36]
    float* __restrict__ out)        // [N, 1024, 1280]
{
    const int H = 512, W = 640;
    const size_t HW = (size_t)H * W;
    const int n  = blockIdx.z;
    const int h0 = blockIdx.y * SH;
    const int cb = blockIdx.x * SW;
    const int tid  = threadIdx.x;
    const int lane = tid & 63;
    const int wv   = tid >> 6;       // wave = row within strip
    const int o    = lane & 15;
    const int krow = lane >> 4;
    const int u    = o >> 2;         // tap-group
    const int q    = o & 3;          // softmax column

    __shared__ half8 s_cv[NR * CW];  // 15,552 B
    __shared__ float s_d[NR * DW];   //  3,912 B

    const float* __restrict__ cvn = cv + (size_t)n * 8 * HW;
    const float* __restrict__ dn  = depth + (size_t)n * HW;

    // ---- stage cv (fp16x8, [row][col][ch]) + depth (f32) with zero halo ----
    for (int i = tid; i < NR * CW; i += 256) {
        const int r = i / CW;
        const int c = i - r * CW;
        const int gh = h0 + r - 1;
        const int gw = cb + c - 1;
        half8 hv = {};
        float dv = 0.0f;
        if ((unsigned)gh < (unsigned)H && (unsigned)gw < (unsigned)W) {
            const float* p = cvn + (size_t)gh * W + gw;
            #pragma unroll
            for (int ch = 0; ch < 8; ++ch) hv[ch] = (_Float16)p[(size_t)ch * HW];
            dv = dn[(size_t)gh * W + gw];
        }
        s_cv[i] = hv;
        s_d[r * DW + c] = dv;
    }

    // ---- conv1 weights as A-fragments: A1[row=och][k], k = tap*8 + c ----
    half8 a1[3];
    #pragma unroll
    for (int ki = 0; ki < 3; ++ki) {
        const int tap = 4 * ki + krow;
        #pragma unroll
        for (int j = 0; j < 8; ++j)
            a1[ki][j] = (tap < 9 && o < 8) ? (_Float16)w1[(o * 8 + j) * 9 + tap]
                                           : (_Float16)0.0f;
    }
    // cv B-fragment per-lane base byte offsets
    int aoff[3];
    #pragma unroll
    for (int ki = 0; ki < 3; ++ki) {
        const int tap0 = 4 * ki + krow;
        const int tap  = tap0 > 8 ? 8 : tap0;
        const int ky   = tap / 3;
        const int kx   = tap - 3 * ky;
        aoff[ki] = ((wv + ky) * CW + o + kx) * 16;
    }
    // b1 for this lane's 4 och (valid for krow<2; others unused junk)
    const float4_t b1q = *reinterpret_cast<const float4_t*>(b1 + (krow & 1) * 4);

    // ---- conv2 weights as B-fragments (only k=0..7 rows live -> krow==0) ----
    half8 b2f[3] = {};
    if (krow == 0) {
        #pragma unroll
        for (int t = 0; t < 3; ++t) {
            const int m = (o + 16 * t) > 35 ? 35 : (o + 16 * t);
            const float4_t wlo = *reinterpret_cast<const float4_t*>(w2 + m * 8);
            const float4_t whi = *reinterpret_cast<const float4_t*>(w2 + m * 8 + 4);
            #pragma unroll
            for (int j = 0; j < 4; ++j) {
                b2f[t][j]     = (_Float16)wlo[j];
                b2f[t][4 + j] = (_Float16)whi[j];
            }
        }
    }
    // 0.25 * log2(e) folded scale; bias pre-scaled into log2 domain
    const float C = 0.25f * 1.44269504f;
    float b2q[3];
    #pragma unroll
    for (int t = 0; t < 3; ++t) {
        const int m = (o + 16 * t) > 35 ? 35 : (o + 16 * t);
        b2q[t] = C * b2[m];
    }
    const bool t2ok = (u == 0);

    // patch tap byte-offsets in s_d (lane-constant): taps {u, u+4, 8}
    int poff[3];
    {
        const int taps[3] = {u, u + 4, 8};
        #pragma unroll
        for (int t = 0; t < 3; ++t) {
            const int ky = taps[t] / 3;
            const int kx = taps[t] - 3 * ky;
            poff[t] = ((wv + ky) * DW + kx) * 4;
        }
    }

    __syncthreads();

    const char* cvb = (const char*)s_cv;
    const char* sdb = (const char*)s_d;
    const float4_t zero4 = {0.0f, 0.0f, 0.0f, 0.0f};

    // ---- 10 sets of 16 pixels per wave-row; unroll 2 for cross-set ILP ----
    #pragma unroll 2
    for (int ps = 0; ps < SW / 16; ++ps) {
        // conv1: D1[och][pix]  (A = weights, B = cv tile)
        float4_t acc1 = zero4;
        #pragma unroll
        for (int ki = 0; ki < 3; ++ki) {
            const half8 bcv = *(const half8*)(cvb + aoff[ki] + ps * 256);
            acc1 = __builtin_amdgcn_mfma_f32_16x16x32_f16(a1[ki], bcv, acc1, 0, 0, 0);
        }

        // X = relu(acc1 + b1); pack to fp16; xor-16 exchange completes A2 (k=0..7)
        union { half8 v; uint32_t u32[4]; } a2;
        #pragma unroll
        for (int r = 0; r < 4; ++r)
            a2.v[r] = (_Float16)fmaxf(acc1[r] + b1q[r], 0.0f);
        const uint32_t p0 = (uint32_t)__shfl_xor((int)a2.u32[0], 16);
        const uint32_t p1 = (uint32_t)__shfl_xor((int)a2.u32[1], 16);
        a2.u32[2] = p0;
        a2.u32[3] = p1;

        // conv2: D2[pix][m], 3 m-tiles
        float4_t d2[3];
        #pragma unroll
        for (int t = 0; t < 3; ++t)
            d2[t] = __builtin_amdgcn_mfma_f32_16x16x32_f16(a2.v, b2f[t], zero4, 0, 0, 0);

        // softmax without max-subtraction (shift-invariant; |logit| << 126):
        // e = exp2(C*(d2 + b2)), masked tap -> exp2(-3e38) = 0
        float se[4], sp[4];
        const int cbase = (ps * 16 + 4 * krow) * 4;
        #pragma unroll
        for (int r = 0; r < 4; ++r) {
            const float ml0 = fmaf(d2[0][r], C, b2q[0]);
            const float ml1 = fmaf(d2[1][r], C, b2q[1]);
            const float ml2 = t2ok ? fmaf(d2[2][r], C, b2q[2]) : -3.0e38f;
            const float e0 = fexp2(ml0);
            const float e1 = fexp2(ml1);
            const float e2 = fexp2(ml2);
            const float pt0 = *(const float*)(sdb + poff[0] + cbase + r * 4);
            const float pt1 = *(const float*)(sdb + poff[1] + cbase + r * 4);
            const float pt2 = *(const float*)(sdb + poff[2] + cbase + r * 4);
            se[r] = e0 + e1 + e2;
            sp[r] = e0 * pt0 + e1 * pt1 + e2 * pt2;
        }
        // VALU-pipe rotate-reduce over the 4 tap-group lanes (ror4 + ror8)
        #pragma unroll
        for (int r = 0; r < 4; ++r) {
            se[r] = rr_add<ROR8>(rr_add<ROR4>(se[r]));
            sp[r] = rr_add<ROR8>(rr_add<ROR4>(sp[r]));
        }

        float res[4];
        #pragma unroll
        for (int r = 0; r < 4; ++r) res[r] = sp[r] * __builtin_amdgcn_rcpf(se[r]);

        // each lane stores its unique (pixel = 4*krow + u, q) output
        const float v01 = (u & 1) ? res[1] : res[0];
        const float v23 = (u & 1) ? res[3] : res[2];
        const float val = (u & 2) ? v23 : v01;
        const int prow = h0 + wv;
        const int pcol = cb + ps * 16 + 4 * krow + u;
        out[((size_t)n * 1024 + (size_t)(2 * prow + (q >> 1))) * 1280
            + (size_t)(2 * pcol + (q & 1))] = val;
    }
}

extern "C" void kernel_launch(void* const* d_in, const int* in_sizes, int n_in,
                              void* d_out, int out_size, void* d_ws, size_t ws_size,
                              hipStream_t stream) {
    (void)in_sizes; (void)n_in; (void)out_size; (void)d_ws; (void)ws_size;
    const float* depth = (const float*)d_in[0];
    const float* cv    = (const float*)d_in[1];
    const float* w1    = (const float*)d_in[2];
    const float* b1    = (const float*)d_in[3];
    const float* w2    = (const float*)d_in[4];
    const float* b2    = (const float*)d_in[5];
    float* out = (float*)d_out;

    dim3 grid(640 / SW, 512 / SH, 4);   // (4, 128, 4) = 2048 blocks
    dim3 block(256);
    hipLaunchKernelGGL(depth_up_fused, grid, block, 0, stream,
                       depth, cv, w1, b1, w2, b2, out);
}